// Round 8
// baseline (3933.178 us; speedup 1.0000x reference)
//
#include <hip/hip_runtime.h>
#include <hip/hip_bf16.h>
#include <math.h>

#define NV 50000
#define NE 256
#define NH 256
#define NT 20
#define NB 64
#define NL 512
#define TAG_START 18
#define TAG_STOP 19
#define NEGV -10000.0f

typedef unsigned short ushortT;
typedef __attribute__((ext_vector_type(4))) float f32x4;
typedef __attribute__((ext_vector_type(8))) short short8;

#define PINV(x) asm volatile("" : "+v"(x))

__device__ __forceinline__ float sigf_slow(float x) { return 1.0f / (1.0f + expf(-x)); }
__device__ __forceinline__ float fsig(float x) { return 1.0f / (1.0f + __expf(-x)); }
__device__ __forceinline__ float ftanh(float x) { return 1.0f - 2.0f / (1.0f + __expf(2.0f * x)); }
__device__ __forceinline__ ushortT f2bf(float f) {
    unsigned int u = __float_as_uint(f);
    u += 0x7fffu + ((u >> 16) & 1u);
    return (ushortT)(u >> 16);
}
__device__ __forceinline__ float bf2f(unsigned int bits16) {
    return __uint_as_float(bits16 << 16);
}

// ---- weight load into literal AGPRs (a0..a127) ----------------------------
#define WRW(A0,A1,A2,A3,PTR) do {                                   \
    int4 _u = *(const int4*)(PTR);                                  \
    asm volatile("v_accvgpr_write_b32 a" #A0 ", %0\n\t"             \
                 "v_accvgpr_write_b32 a" #A1 ", %1\n\t"             \
                 "v_accvgpr_write_b32 a" #A2 ", %2\n\t"             \
                 "v_accvgpr_write_b32 a" #A3 ", %3"                 \
                 :: "v"(_u.x), "v"(_u.y), "v"(_u.z), "v"(_u.w)      \
                 : "a" #A0, "a" #A1, "a" #A2, "a" #A3);             \
} while (0)

#define ACLOB128 \
 "a0","a1","a2","a3","a4","a5","a6","a7","a8","a9","a10","a11","a12","a13","a14","a15",\
 "a16","a17","a18","a19","a20","a21","a22","a23","a24","a25","a26","a27","a28","a29","a30","a31",\
 "a32","a33","a34","a35","a36","a37","a38","a39","a40","a41","a42","a43","a44","a45","a46","a47",\
 "a48","a49","a50","a51","a52","a53","a54","a55","a56","a57","a58","a59","a60","a61","a62","a63",\
 "a64","a65","a66","a67","a68","a69","a70","a71","a72","a73","a74","a75","a76","a77","a78","a79",\
 "a80","a81","a82","a83","a84","a85","a86","a87","a88","a89","a90","a91","a92","a93","a94","a95",\
 "a96","a97","a98","a99","a100","a101","a102","a103","a104","a105","a106","a107","a108","a109","a110","a111",\
 "a112","a113","a114","a115","a116","a117","a118","a119","a120","a121","a122","a123","a124","a125","a126","a127"

// 8 MFMAs for one k-tile: acc in VGPR ("+v"), B for nt0-3 in literal AGPRs,
// B for nt4-7 via VGPR operands (LDS-loaded / streamed).
#define MFMA_KT(PRE, POST, W0a,W0b, W1a,W1b, W2a,W2b, W3a,W3b, AF, WL4, WL5, S6, S7) \
  asm volatile(PRE                                                                    \
    "v_mfma_f32_16x16x32_bf16 %0, %8, a[" #W0a ":" #W0b "], %0\n\t"                   \
    "v_mfma_f32_16x16x32_bf16 %1, %8, a[" #W1a ":" #W1b "], %1\n\t"                   \
    "v_mfma_f32_16x16x32_bf16 %2, %8, a[" #W2a ":" #W2b "], %2\n\t"                   \
    "v_mfma_f32_16x16x32_bf16 %3, %8, a[" #W3a ":" #W3b "], %3\n\t"                   \
    "v_mfma_f32_16x16x32_bf16 %4, %8, %9, %4\n\t"                                     \
    "v_mfma_f32_16x16x32_bf16 %5, %8, %10, %5\n\t"                                    \
    "v_mfma_f32_16x16x32_bf16 %6, %8, %11, %6\n\t"                                    \
    "v_mfma_f32_16x16x32_bf16 %7, %8, %12, %7" POST                                   \
    : "+v"(acc0), "+v"(acc1), "+v"(acc2), "+v"(acc3),                                 \
      "+v"(acc4), "+v"(acc5), "+v"(acc6), "+v"(acc7)                                  \
    : "v"(AF), "v"(WL4), "v"(WL5), "v"(S6), "v"(S7)                                   \
    : ACLOB128)

#define BARRIER_LGKM() asm volatile("s_waitcnt lgkmcnt(0)\n\ts_barrier" ::: "memory")

// ===========================================================================
// FAST PATH
// ===========================================================================

__global__ __launch_bounds__(256) void k_cvtw(
    const float* __restrict__ whh_f, const float* __restrict__ whh_b,
    const float* __restrict__ wih_f, const float* __restrict__ wih_b,
    ushortT* __restrict__ whh16, ushortT* __restrict__ wih16)
{
    int idx = blockIdx.x * 256 + threadIdx.x;     // < 262144
    const float* s; ushortT* d;
    switch (blockIdx.y) {
        case 0: s = whh_f; d = whh16;            break;
        case 1: s = whh_b; d = whh16 + 262144;   break;
        case 2: s = wih_f; d = wih16;            break;
        default: s = wih_b; d = wih16 + 262144;  break;
    }
    d[idx] = f2bf(s[idx]);
}

__global__ __launch_bounds__(1024) void k_bias(
    const float* __restrict__ bih_f, const float* __restrict__ bhh_f,
    const float* __restrict__ bih_b, const float* __restrict__ bhh_b,
    float* __restrict__ biasc)
{
    int n = threadIdx.x;
    if (blockIdx.x == 0) biasc[n] = bih_f[n] + bhh_f[n];
    else                 biasc[1024 + n] = bih_b[n] + bhh_b[n];
}

// K-gin: gin[dirg][t][col*16 + row] = x_t @ Wih^T + bias  (bf16 MFMA)
__global__
__attribute__((amdgpu_flat_work_group_size(512, 512)))
__attribute__((amdgpu_waves_per_eu(2, 2)))
void k_gin_mfma(
    const int* __restrict__ sent, const int* __restrict__ lens,
    const float* __restrict__ emb, const ushortT* __restrict__ wih16,
    const float* __restrict__ biasc, float* __restrict__ gin,
    int chunk_start, int CH)
{
    const int g = blockIdx.x, tsub = blockIdx.y;
    const int dir = blockIdx.z >> 1, half = blockIdx.z & 1;
    const int gmax = lens[g * 16];
    const int tt0 = tsub * 16;
    if (chunk_start + tt0 >= gmax) return;

    const int tid = threadIdx.x;
    const int w = tid >> 6, l = tid & 63, lr = l & 15, lg = l >> 4;

    __shared__ char x_raw[16 * 512];

    const int ucol = half * 128 + w * 16 + lr;
    short8 bfr[4][8];
    float bias_l[4];
    const ushortT* wsrc = wih16 + dir * 262144;
#pragma unroll
    for (int nt = 0; nt < 4; ++nt) {
        int col = nt * 256 + ucol;
        bias_l[nt] = biasc[dir * 1024 + col];
#pragma unroll
        for (int kt = 0; kt < 8; ++kt)
            bfr[nt][kt] = *(const short8*)(wsrc + (size_t)col * 256 + kt * 32 + lg * 8);
    }
#pragma unroll
    for (int nt = 0; nt < 4; ++nt) {
        PINV(bias_l[nt]);
#pragma unroll
        for (int kt = 0; kt < 8; ++kt) PINV(bfr[nt][kt]);
    }

    const int srow = tid >> 5, sseg = tid & 31;
    const int slen = lens[g * 16 + srow];
    const int sb = (g * 16 + srow) * 512;

    for (int i = 0; i < 16; ++i) {
        int tg = chunk_start + tt0 + i;
        if (tg >= gmax) break;

        int tsrc = dir ? (slen - 1 - tg) : tg;
        if (tsrc < 0) tsrc = 0;
        if (tsrc > 511) tsrc = 511;
        int tok = sent[sb + tsrc];
        const float* es = emb + (size_t)tok * 256 + sseg * 8;
        float4 e0 = *(const float4*)es;
        float4 e1 = *(const float4*)(es + 4);
        short8 xv;
        xv[0] = (short)f2bf(e0.x); xv[1] = (short)f2bf(e0.y);
        xv[2] = (short)f2bf(e0.z); xv[3] = (short)f2bf(e0.w);
        xv[4] = (short)f2bf(e1.x); xv[5] = (short)f2bf(e1.y);
        xv[6] = (short)f2bf(e1.z); xv[7] = (short)f2bf(e1.w);
        int sa = (srow * 512 + sseg * 16) ^ ((srow & 7) << 4);
        *(short8*)&x_raw[sa] = xv;
        __syncthreads();

        short8 af[8];
#pragma unroll
        for (int kt = 0; kt < 8; ++kt) {
            int a = (lr * 512 + kt * 64 + lg * 16) ^ ((lr & 7) << 4);
            af[kt] = *(const short8*)&x_raw[a];
        }
        f32x4 acc[4];
#pragma unroll
        for (int nt = 0; nt < 4; ++nt) {
            acc[nt][0] = bias_l[nt]; acc[nt][1] = bias_l[nt];
            acc[nt][2] = bias_l[nt]; acc[nt][3] = bias_l[nt];
        }
#pragma unroll
        for (int kt = 0; kt < 8; ++kt)
#pragma unroll
            for (int nt = 0; nt < 4; ++nt)
                acc[nt] = __builtin_amdgcn_mfma_f32_16x16x32_bf16(af[kt], bfr[nt][kt], acc[nt], 0, 0, 0);

        float* ginp = gin + ((size_t)((dir * 4 + g) * CH + (tt0 + i))) * 16384;
#pragma unroll
        for (int nt = 0; nt < 4; ++nt)
            *(f32x4*)(ginp + (nt * 256 + ucol) * 16 + lg * 4) = acc[nt];
        __syncthreads();
    }
}

// K-rec v3: ONE WG (512 thr) per (group,dir) — no cross-CU exchange.
//   Weights: gates i,f in AGPR a0-a127; gate g in LDS (128 KB); gate o
//   streamed from L2 per step (rotating reg buffers). acc in VGPRs.
__global__
__attribute__((amdgpu_flat_work_group_size(512, 512)))
__attribute__((amdgpu_waves_per_eu(2, 2)))
void k_rec_mfma(
    const int* __restrict__ lens, const ushortT* __restrict__ whh16,
    const float* __restrict__ gin, ushortT* __restrict__ hout,
    ushortT* __restrict__ st_h, float* __restrict__ st_c,
    int chunk_start, int CH)
{
    const int g = blockIdx.x, dir = blockIdx.y;
    const int gmax = lens[g * 16];
    const int nsteps = min(CH, gmax - chunk_start);
    if (nsteps <= 0) return;

    const int tid = threadIdx.x;
    const int w = tid >> 6, l = tid & 63, lr = l & 15, lg = l >> 4;
    const int dirg = dir * 4 + g;

    __shared__ char h_s[2][8192];        // h, double-buffered, XOR-swizzled
    __shared__ char wl_s[2][65536];      // gate-g weights (nt4, nt5)

    int lenr[4];
#pragma unroll
    for (int r = 0; r < 4; ++r) lenr[r] = lens[g * 16 + lg * 4 + r];

    const ushortT* wsrc = whh16 + dir * 262144;

    // ---- AGPR weights: nt0-3 (gates i,f). frag(nt,kt) -> a[nt*32+kt*4] ----
    {
        const ushortT* q0 = wsrc + (size_t)(0   + w * 32 +  0 + lr) * 256 + lg * 8;  // nt0
        const ushortT* q1 = wsrc + (size_t)(0   + w * 32 + 16 + lr) * 256 + lg * 8;  // nt1
        const ushortT* q2 = wsrc + (size_t)(256 + w * 32 +  0 + lr) * 256 + lg * 8;  // nt2
        const ushortT* q3 = wsrc + (size_t)(256 + w * 32 + 16 + lr) * 256 + lg * 8;  // nt3
        WRW(  0,  1,  2,  3, q0 +   0); WRW(  4,  5,  6,  7, q0 +  32);
        WRW(  8,  9, 10, 11, q0 +  64); WRW( 12, 13, 14, 15, q0 +  96);
        WRW( 16, 17, 18, 19, q0 + 128); WRW( 20, 21, 22, 23, q0 + 160);
        WRW( 24, 25, 26, 27, q0 + 192); WRW( 28, 29, 30, 31, q0 + 224);
        WRW( 32, 33, 34, 35, q1 +   0); WRW( 36, 37, 38, 39, q1 +  32);
        WRW( 40, 41, 42, 43, q1 +  64); WRW( 44, 45, 46, 47, q1 +  96);
        WRW( 48, 49, 50, 51, q1 + 128); WRW( 52, 53, 54, 55, q1 + 160);
        WRW( 56, 57, 58, 59, q1 + 192); WRW( 60, 61, 62, 63, q1 + 224);
        WRW( 64, 65, 66, 67, q2 +   0); WRW( 68, 69, 70, 71, q2 +  32);
        WRW( 72, 73, 74, 75, q2 +  64); WRW( 76, 77, 78, 79, q2 +  96);
        WRW( 80, 81, 82, 83, q2 + 128); WRW( 84, 85, 86, 87, q2 + 160);
        WRW( 88, 89, 90, 91, q2 + 192); WRW( 92, 93, 94, 95, q2 + 224);
        WRW( 96, 97, 98, 99, q3 +   0); WRW(100,101,102,103, q3 +  32);
        WRW(104,105,106,107, q3 +  64); WRW(108,109,110,111, q3 +  96);
        WRW(112,113,114,115, q3 + 128); WRW(116,117,118,119, q3 + 160);
        WRW(120,121,122,123, q3 + 192); WRW(124,125,126,127, q3 + 224);
    }

    // ---- LDS weights: nt4,5 (gate g), swizzled [c128][k] ------------------
    for (int it = 0; it < 16; ++it) {
        int id = tid * 16 + it;                 // 8192 16B-chunks
        int ntl = id >> 12;
        int rem = id & 4095;
        int cc = rem >> 5, j = rem & 31;
        int col = 512 + ((cc >> 4) * 32) + ntl * 16 + (cc & 15);
        int4 v = *(const int4*)(wsrc + (size_t)col * 256 + j * 8);
        int dst = (cc * 512 + j * 16) ^ ((cc & 7) << 4);
        *(int4*)&wl_s[ntl][dst] = v;
    }

    // ---- state init / restore --------------------------------------------
    float c[2][4];
    if (chunk_start == 0) {
#pragma unroll
        for (int s = 0; s < 2; ++s)
#pragma unroll
            for (int r = 0; r < 4; ++r) c[s][r] = 0.0f;
        for (int i = tid; i < 2048; i += 512) ((int*)h_s[0])[i] = 0;
    } else {
        const float* cs = st_c + ((size_t)dirg * 512 + tid) * 8;
#pragma unroll
        for (int s = 0; s < 2; ++s)
#pragma unroll
            for (int r = 0; r < 4; ++r) c[s][r] = cs[s * 4 + r];
        const int* hs = (const int*)st_h + dirg * 2048;
        for (int i = tid; i < 2048; i += 512) ((int*)h_s[0])[i] = hs[i];
    }
    __syncthreads();

    // ---- per-lane constants ----------------------------------------------
    const float* ginp = gin + (size_t)dirg * CH * 16384;
    const int co0 = (0   + w * 32 +  0 + lr) * 16 + lg * 4;
    const int co1 = (0   + w * 32 + 16 + lr) * 16 + lg * 4;
    const int co2 = (256 + w * 32 +  0 + lr) * 16 + lg * 4;
    const int co3 = (256 + w * 32 + 16 + lr) * 16 + lg * 4;
    const int co4 = (512 + w * 32 +  0 + lr) * 16 + lg * 4;
    const int co5 = (512 + w * 32 + 16 + lr) * 16 + lg * 4;
    const int co6 = (768 + w * 32 +  0 + lr) * 16 + lg * 4;
    const int co7 = (768 + w * 32 + 16 + lr) * 16 + lg * 4;
    const int c128 = w * 16 + lr;
    const int u0 = w * 32 + lr, u1 = w * 32 + 16 + lr;

    const ushortT* ps6 = wsrc + (size_t)(768 + w * 32 +  0 + lr) * 256 + lg * 8;
    const ushortT* ps7 = wsrc + (size_t)(768 + w * 32 + 16 + lr) * 256 + lg * 8;

#define LDH(KT)  (*(const short8*)&hb[(lr * 512 + (KT) * 64 + lg * 16) ^ ((lr & 7) << 4)])
#define LDW(NT,KT) (*(const short8*)&wl_s[NT][(c128 * 512 + (KT) * 64 + lg * 16) ^ ((c128 & 7) << 4)])

    // ---- prologue: streamed gate-o frags kt0-3 + gv for tt=0 -------------
    short8 s6A0 = *(const short8*)(ps6 +   0), s7A0 = *(const short8*)(ps7 +   0);
    short8 s6A1 = *(const short8*)(ps6 +  32), s7A1 = *(const short8*)(ps7 +  32);
    short8 s6B0 = *(const short8*)(ps6 +  64), s7B0 = *(const short8*)(ps7 +  64);
    short8 s6B1 = *(const short8*)(ps6 +  96), s7B1 = *(const short8*)(ps7 +  96);
    f32x4 gv0 = *(const f32x4*)(ginp + co0);
    f32x4 gv1 = *(const f32x4*)(ginp + co1);
    f32x4 gv2 = *(const f32x4*)(ginp + co2);
    f32x4 gv3 = *(const f32x4*)(ginp + co3);
    f32x4 gv4 = *(const f32x4*)(ginp + co4);
    f32x4 gv5 = *(const f32x4*)(ginp + co5);
    f32x4 gv6 = *(const f32x4*)(ginp + co6);
    f32x4 gv7 = *(const f32x4*)(ginp + co7);

    int p = 0;
    for (int tt = 0; tt < nsteps; ++tt) {
        const int t_glob = chunk_start + tt;
        asm volatile("" : "+v"(ps6), "+v"(ps7));   // block LICM of refills

        f32x4 acc0 = gv0, acc1 = gv1, acc2 = gv2, acc3 = gv3;
        f32x4 acc4 = gv4, acc5 = gv5, acc6 = gv6, acc7 = gv7;

        const char* hb = h_s[p];
        short8 af, w4, w5;

        af = LDH(0); w4 = LDW(0,0); w5 = LDW(1,0);
        MFMA_KT("s_nop 1\n\t", "",   0,  3, 32, 35, 64, 67,  96, 99, af, w4, w5, s6A0, s7A0);
        af = LDH(1); w4 = LDW(0,1); w5 = LDW(1,1);
        MFMA_KT("", "",              4,  7, 36, 39, 68, 71, 100,103, af, w4, w5, s6A1, s7A1);
        s6A0 = *(const short8*)(ps6 + 128); s7A0 = *(const short8*)(ps7 + 128);
        s6A1 = *(const short8*)(ps6 + 160); s7A1 = *(const short8*)(ps7 + 160);
        af = LDH(2); w4 = LDW(0,2); w5 = LDW(1,2);
        MFMA_KT("", "",              8, 11, 40, 43, 72, 75, 104,107, af, w4, w5, s6B0, s7B0);
        af = LDH(3); w4 = LDW(0,3); w5 = LDW(1,3);
        MFMA_KT("", "",             12, 15, 44, 47, 76, 79, 108,111, af, w4, w5, s6B1, s7B1);
        s6B0 = *(const short8*)(ps6 + 192); s7B0 = *(const short8*)(ps7 + 192);
        s6B1 = *(const short8*)(ps6 + 224); s7B1 = *(const short8*)(ps7 + 224);
        af = LDH(4); w4 = LDW(0,4); w5 = LDW(1,4);
        MFMA_KT("", "",             16, 19, 48, 51, 80, 83, 112,115, af, w4, w5, s6A0, s7A0);
        af = LDH(5); w4 = LDW(0,5); w5 = LDW(1,5);
        MFMA_KT("", "",             20, 23, 52, 55, 84, 87, 116,119, af, w4, w5, s6A1, s7A1);
        af = LDH(6); w4 = LDW(0,6); w5 = LDW(1,6);
        MFMA_KT("", "",             24, 27, 56, 59, 88, 91, 120,123, af, w4, w5, s6B0, s7B0);
        af = LDH(7); w4 = LDW(0,7); w5 = LDW(1,7);
        MFMA_KT("", "\n\ts_nop 7\n\ts_nop 7",
                                    28, 31, 60, 63, 92, 95, 124,127, af, w4, w5, s6B1, s7B1);

        // ---- pointwise (lane owns units u0,u1; rows lg*4+r) --------------
        char* hw = h_s[p ^ 1];
#pragma unroll
        for (int r = 0; r < 4; ++r) {
            float cn = fsig(acc2[r]) * c[0][r] + fsig(acc0[r]) * ftanh(acc4[r]);
            float hn = fsig(acc6[r]) * ftanh(cn);
            c[0][r] = cn;
            ushortT hb16 = f2bf(hn);
            int row = lg * 4 + r;
            *(ushortT*)&hw[(row * 512 + u0 * 2) ^ ((row & 7) << 4)] = hb16;
            if (t_glob < lenr[r]) {
                int tp = dir ? (lenr[r] - 1 - t_glob) : t_glob;
                hout[((size_t)((g * 16 + row) * 512 + tp)) * 512 + dir * 256 + u0] = hb16;
            }
        }
#pragma unroll
        for (int r = 0; r < 4; ++r) {
            float cn = fsig(acc3[r]) * c[1][r] + fsig(acc1[r]) * ftanh(acc5[r]);
            float hn = fsig(acc7[r]) * ftanh(cn);
            c[1][r] = cn;
            ushortT hb16 = f2bf(hn);
            int row = lg * 4 + r;
            *(ushortT*)&hw[(row * 512 + u1 * 2) ^ ((row & 7) << 4)] = hb16;
            if (t_glob < lenr[r]) {
                int tp = dir ? (lenr[r] - 1 - t_glob) : t_glob;
                hout[((size_t)((g * 16 + row) * 512 + tp)) * 512 + dir * 256 + u1] = hb16;
            }
        }

        // ---- prefetch next step (flies across the lgkm-only barrier) -----
        s6A0 = *(const short8*)(ps6 +   0); s7A0 = *(const short8*)(ps7 +   0);
        s6A1 = *(const short8*)(ps6 +  32); s7A1 = *(const short8*)(ps7 +  32);
        s6B0 = *(const short8*)(ps6 +  64); s7B0 = *(const short8*)(ps7 +  64);
        s6B1 = *(const short8*)(ps6 +  96); s7B1 = *(const short8*)(ps7 +  96);
        {
            int ttn = (tt + 1 < nsteps) ? (tt + 1) : tt;
            const float* gp = ginp + (size_t)ttn * 16384;
            gv0 = *(const f32x4*)(gp + co0); gv1 = *(const f32x4*)(gp + co1);
            gv2 = *(const f32x4*)(gp + co2); gv3 = *(const f32x4*)(gp + co3);
            gv4 = *(const f32x4*)(gp + co4); gv5 = *(const f32x4*)(gp + co5);
            gv6 = *(const f32x4*)(gp + co6); gv7 = *(const f32x4*)(gp + co7);
        }
        BARRIER_LGKM();
        p ^= 1;
    }
#undef LDH
#undef LDW

    // ---- save state -------------------------------------------------------
    float* cs = st_c + ((size_t)dirg * 512 + tid) * 8;
#pragma unroll
    for (int s = 0; s < 2; ++s)
#pragma unroll
        for (int r = 0; r < 4; ++r) cs[s * 4 + r] = c[s][r];
    int* hs = (int*)st_h + dirg * 2048;
    for (int i = tid; i < 2048; i += 512) hs[i] = ((int*)h_s[p])[i];
}

// K-scores: scores[b,t,:] = h[b,t,:] (bf16) @ w_out^T + b_out  (t < len)
__global__ __launch_bounds__(256) void k_scores_bf(
    const int* __restrict__ lens, const ushortT* __restrict__ hout,
    const float* __restrict__ w_out, const float* __restrict__ b_out,
    float* __restrict__ scores)
{
    const int b = blockIdx.y;
    const int t0 = blockIdx.x * 32;
    const int len = lens[b];
    if (t0 >= len) return;

    __shared__ float w_s[20 * 513];
    __shared__ float row_s[512];
    __shared__ float part_s[20][9];
    __shared__ float bo_s[20];

    const int tid = threadIdx.x;
    for (int e = tid; e < 20 * 512; e += 256) w_s[(e >> 9) * 513 + (e & 511)] = w_out[e];
    if (tid < 20) bo_s[tid] = b_out[tid];
    __syncthreads();

    const int tend = min(t0 + 32, len);
    const int tag = tid >> 3, sl = tid & 7;
    for (int t = t0; t < tend; ++t) {
        const ushortT* hr = hout + ((size_t)(b * 512 + t)) * 512;
        unsigned int v = ((const unsigned int*)hr)[tid];
        row_s[tid * 2] = bf2f(v & 0xffffu);
        row_s[tid * 2 + 1] = bf2f(v >> 16);
        __syncthreads();
        if (tid < 160) {
            float s = 0.0f;
#pragma unroll 8
            for (int j = 0; j < 64; ++j) {
                int k = sl + (((j + tag) & 63) << 3);
                s = fmaf(w_s[tag * 513 + k], row_s[k], s);
            }
            part_s[tag][sl] = s;
        }
        __syncthreads();
        if (tid < 20) {
            float s = bo_s[tid];
#pragma unroll
            for (int j = 0; j < 8; ++j) s += part_s[tid][j];
            scores[((size_t)(b * 512 + t)) * 20 + tid] = s;
        }
        __syncthreads();
    }
}

__global__ __launch_bounds__(64) void k_viterbi_s(
    const int* __restrict__ lens, const float* __restrict__ scores,
    const float* __restrict__ trans, float* __restrict__ out)
{
    const int b = blockIdx.x;
    const int lane = threadIdx.x;
    const int len = lens[b];

    __shared__ float tr_s[20][21];
    __shared__ float fv_s[20];
    __shared__ float term_s[20];
    __shared__ unsigned char bp_s[512][20];
    __shared__ unsigned char path_s[512];

    for (int e = lane; e < 400; e += 64) tr_s[e / 20][e % 20] = trans[e];
    if (lane < 20) fv_s[lane] = (lane == TAG_START) ? 0.0f : NEGV;
    __syncthreads();

    const float* sc = scores + ((size_t)(b << 9)) * 20;
    for (int t = 0; t < len; ++t) {
        float m = 0.0f; int arg = 0;
        if (lane < 20) {
            m = fv_s[0] + tr_s[lane][0]; arg = 0;
#pragma unroll
            for (int k = 1; k < 20; ++k) {
                float v = fv_s[k] + tr_s[lane][k];
                if (v > m) { m = v; arg = k; }
            }
            m += sc[t * 20 + lane];
        }
        __syncthreads();
        if (lane < 20) { fv_s[lane] = m; bp_s[t][lane] = (unsigned char)arg; }
        __syncthreads();
    }

    if (lane < 20) term_s[lane] = fv_s[lane] + tr_s[TAG_STOP][lane];
    __syncthreads();

    if (lane == 0) {
        float m = term_s[0]; int arg = 0;
        for (int k = 1; k < 20; ++k) if (term_s[k] > m) { m = term_s[k]; arg = k; }
        out[b] = m;
        int cur = arg;
        path_s[len - 1] = (unsigned char)cur;
        for (int j = len - 1; j >= 1; --j) {
            cur = bp_s[j][cur];
            path_s[j - 1] = (unsigned char)cur;
        }
    }
    __syncthreads();

    float* po = out + NB + ((size_t)b << 9);
    for (int p = lane; p < NL; p += 64) po[p] = (p < len) ? (float)path_s[p] : 0.0f;
}

// ===========================================================================
// FALLBACK PATH (round-2 proven)
// ===========================================================================
__global__ __launch_bounds__(256) void k_transpose_fb(
    const float* __restrict__ whh_f, const float* __restrict__ whh_b,
    const float* __restrict__ wih_f, const float* __restrict__ wih_b,
    float* __restrict__ thh_f, float* __restrict__ thh_b,
    float* __restrict__ tih_f, float* __restrict__ tih_b)
{
    int e = blockIdx.x * 256 + threadIdx.x;
    const float* wm; float* wt;
    switch (blockIdx.y) {
        case 0: wm = whh_f; wt = thh_f; break;
        case 1: wm = whh_b; wt = thh_b; break;
        case 2: wm = wih_f; wt = tih_f; break;
        default: wm = wih_b; wt = tih_b; break;
    }
    int n = e >> 8, k = e & 255;
    wt[k * 1024 + n] = wm[e];
}

__global__ __launch_bounds__(1024) void k_rec_fb(
    const int* __restrict__ sent, const int* __restrict__ lens,
    const float* __restrict__ emb,
    const float* __restrict__ thh_f, const float* __restrict__ thh_b,
    const float* __restrict__ tih_f, const float* __restrict__ tih_b,
    const float* __restrict__ b_ih_f, const float* __restrict__ b_hh_f,
    const float* __restrict__ b_ih_b, const float* __restrict__ b_hh_b,
    const float* __restrict__ w_out,
    float* __restrict__ sc_f, float* __restrict__ sc_b)
{
    const int b = blockIdx.x, dir = blockIdx.y;
    const int len = lens[b];
    const int n = threadIdx.x;
    const float* Whh = dir ? thh_b : thh_f;
    const float* Wih = dir ? tih_b : tih_f;
    const float* bi = dir ? b_ih_b : b_ih_f;
    const float* bh = dir ? b_hh_b : b_hh_f;
    float* scout = dir ? sc_b : sc_f;

    __shared__ float x_s[256];
    __shared__ float h_s[256];
    __shared__ float g_s[1024];
    __shared__ float bias_s[1024];
    __shared__ float wout_s[20 * 257];
    __shared__ float part_s[20][8];

    bias_s[n] = bi[n] + bh[n];
    for (int e = n; e < 20 * 256; e += 1024)
        wout_s[(e >> 8) * 257 + (e & 255)] = w_out[(e >> 8) * 512 + dir * 256 + (e & 255)];
    if (n < 256) h_s[n] = 0.0f;
    float c = 0.0f;
    __syncthreads();

    const int sbase = b << 9;
    for (int t = 0; t < len; ++t) {
        if (n < 256) {
            int ti = dir ? (len - 1 - t) : t;
            int tok = sent[sbase + ti];
            x_s[n] = emb[(size_t)tok * NE + n];
        }
        __syncthreads();
        float acc = bias_s[n];
        const float* wi = Wih + n;
        const float* wh = Whh + n;
#pragma unroll 8
        for (int k = 0; k < 256; ++k) {
            acc = fmaf(wh[(size_t)(k << 10)], h_s[k], acc);
            acc = fmaf(wi[(size_t)(k << 10)], x_s[k], acc);
        }
        g_s[n] = acc;
        __syncthreads();
        if (n < 256) {
            float ig = g_s[n], fg = g_s[n + 256], gg = g_s[n + 512], og = g_s[n + 768];
            float cn = sigf_slow(fg) * c + sigf_slow(ig) * tanhf(gg);
            float hn = sigf_slow(og) * tanhf(cn);
            c = cn; h_s[n] = hn;
        }
        __syncthreads();
        if (n < 160) {
            const int tag = n >> 3, sl = n & 7;
            const float* wrow = wout_s + tag * 257;
            float s = 0.0f;
#pragma unroll 8
            for (int j = 0; j < 32; ++j) { int k = sl + (j << 3); s = fmaf(wrow[k], h_s[k], s); }
            part_s[tag][sl] = s;
        }
        __syncthreads();
        if (n < 20) {
            float s = part_s[n][0];
#pragma unroll
            for (int j = 1; j < 8; ++j) s += part_s[n][j];
            int tp = dir ? (len - 1 - t) : t;
            scout[(size_t)(sbase + tp) * 20 + n] = s;
        }
    }
}

__global__ __launch_bounds__(64) void k_viterbi_fb(
    const int* __restrict__ lens,
    const float* __restrict__ sc_f, const float* __restrict__ sc_b,
    const float* __restrict__ b_out, const float* __restrict__ trans,
    float* __restrict__ out)
{
    const int b = blockIdx.x;
    const int lane = threadIdx.x;
    const int len = lens[b];

    __shared__ float tr_s[20][21];
    __shared__ float fv_s[20];
    __shared__ float term_s[20];
    __shared__ float bo_s[20];
    __shared__ unsigned char bp_s[512][20];
    __shared__ unsigned char path_s[512];

    for (int e = lane; e < 400; e += 64) tr_s[e / 20][e % 20] = trans[e];
    if (lane < 20) { fv_s[lane] = (lane == TAG_START) ? 0.0f : NEGV; bo_s[lane] = b_out[lane]; }
    __syncthreads();

    const size_t sb = (size_t)(b << 9) * 20;
    for (int t = 0; t < len; ++t) {
        float m = 0.0f; int arg = 0;
        if (lane < 20) {
            m = fv_s[0] + tr_s[lane][0]; arg = 0;
#pragma unroll
            for (int k = 1; k < 20; ++k) {
                float v = fv_s[k] + tr_s[lane][k];
                if (v > m) { m = v; arg = k; }
            }
            m += sc_f[sb + t * 20 + lane] + sc_b[sb + t * 20 + lane] + bo_s[lane];
        }
        __syncthreads();
        if (lane < 20) { fv_s[lane] = m; bp_s[t][lane] = (unsigned char)arg; }
        __syncthreads();
    }
    if (lane < 20) term_s[lane] = fv_s[lane] + tr_s[TAG_STOP][lane];
    __syncthreads();
    if (lane == 0) {
        float m = term_s[0]; int arg = 0;
        for (int k = 1; k < 20; ++k) if (term_s[k] > m) { m = term_s[k]; arg = k; }
        out[b] = m;
        int cur = arg;
        path_s[len - 1] = (unsigned char)cur;
        for (int j = len - 1; j >= 1; --j) { cur = bp_s[j][cur]; path_s[j - 1] = (unsigned char)cur; }
    }
    __syncthreads();
    float* po = out + NB + ((size_t)b << 9);
    for (int p = lane; p < NL; p += 64) po[p] = (p < len) ? (float)path_s[p] : 0.0f;
}

// ===========================================================================
extern "C" void kernel_launch(void* const* d_in, const int* in_sizes, int n_in,
                              void* d_out, int out_size, void* d_ws, size_t ws_size,
                              hipStream_t stream)
{
    const int*   sent   = (const int*)d_in[0];
    const int*   lens   = (const int*)d_in[1];
    const float* emb    = (const float*)d_in[2];
    const float* w_ih_f = (const float*)d_in[3];
    const float* w_hh_f = (const float*)d_in[4];
    const float* b_ih_f = (const float*)d_in[5];
    const float* b_hh_f = (const float*)d_in[6];
    const float* w_ih_b = (const float*)d_in[7];
    const float* w_hh_b = (const float*)d_in[8];
    const float* b_ih_b = (const float*)d_in[9];
    const float* b_hh_b = (const float*)d_in[10];
    const float* w_out  = (const float*)d_in[11];
    const float* b_out  = (const float*)d_in[12];
    const float* trans  = (const float*)d_in[13];
    float* out = (float*)d_out;

    char* w = (char*)d_ws;
    const size_t base = 38612992;
    int CH = 0;
    const int chs[6] = {512, 256, 192, 128, 64, 32};
    for (int i = 0; i < 6; ++i)
        if (base + (size_t)chs[i] * 524288 <= ws_size) { CH = chs[i]; break; }

    if (CH) {
        ushortT* whh16 = (ushortT*)(w);
        ushortT* wih16 = (ushortT*)(w + 1048576);
        float*   biasc = (float*)(w + 2097152);
        ushortT* st_h  = (ushortT*)(w + 2105344);
        float*   st_c  = (float*)(w + 2170880);
        float*   scores= (float*)(w + 2437120);
        ushortT* hout  = (ushortT*)(w + 5058560);
        float*   gin   = (float*)(w + base);

        k_cvtw<<<dim3(1024, 4), 256, 0, stream>>>(w_hh_f, w_hh_b, w_ih_f, w_ih_b, whh16, wih16);
        k_bias<<<2, 1024, 0, stream>>>(b_ih_f, b_hh_f, b_ih_b, b_hh_b, biasc);

        for (int cs = 0; cs < NL; cs += CH) {
            k_gin_mfma<<<dim3(4, CH / 16, 4), 512, 0, stream>>>(
                sent, lens, emb, wih16, biasc, gin, cs, CH);
            k_rec_mfma<<<dim3(4, 2), 512, 0, stream>>>(
                lens, whh16, gin, hout, st_h, st_c, cs, CH);
        }
        k_scores_bf<<<dim3(16, 64), 256, 0, stream>>>(lens, hout, w_out, b_out, scores);
        k_viterbi_s<<<64, 64, 0, stream>>>(lens, scores, trans, out);
    } else {
        float* ws2   = (float*)d_ws;
        float* thh_f = ws2;
        float* thh_b = thh_f + 262144;
        float* tih_f = thh_b + 262144;
        float* tih_b = tih_f + 262144;
        float* sc_f  = tih_b + 262144;
        float* sc_b  = sc_f + (size_t)NB * NL * NT;

        k_transpose_fb<<<dim3(1024, 4), 256, 0, stream>>>(
            w_hh_f, w_hh_b, w_ih_f, w_ih_b, thh_f, thh_b, tih_f, tih_b);
        k_rec_fb<<<dim3(NB, 2), 1024, 0, stream>>>(
            sent, lens, emb, thh_f, thh_b, tih_f, tih_b,
            b_ih_f, b_hh_f, b_ih_b, b_hh_b, w_out, sc_f, sc_b);
        k_viterbi_fb<<<NB, 64, 0, stream>>>(lens, sc_f, sc_b, b_out, trans, out);
    }
}

// Round 9
// 2399.595 us; speedup vs baseline: 1.6391x; 1.6391x over previous
//
#include <hip/hip_runtime.h>
#include <hip/hip_bf16.h>
#include <math.h>

#define NV 50000
#define NE 256
#define NH 256
#define NT 20
#define NB 64
#define NL 512
#define TAG_START 18
#define TAG_STOP 19
#define NEGV -10000.0f

typedef unsigned short ushortT;
typedef __attribute__((ext_vector_type(4))) float f32x4;
typedef __attribute__((ext_vector_type(8))) short short8;

#define PINV(x) asm volatile("" : "+v"(x))

__device__ __forceinline__ float sigf_slow(float x) { return 1.0f / (1.0f + expf(-x)); }
__device__ __forceinline__ float fsig(float x) { return 1.0f / (1.0f + __expf(-x)); }
__device__ __forceinline__ float ftanh(float x) { return 1.0f - 2.0f / (1.0f + __expf(2.0f * x)); }
__device__ __forceinline__ ushortT f2bf(float f) {
    unsigned int u = __float_as_uint(f);
    u += 0x7fffu + ((u >> 16) & 1u);
    return (ushortT)(u >> 16);
}
__device__ __forceinline__ float bf2f(unsigned int bits16) {
    return __uint_as_float(bits16 << 16);
}

// ===========================================================================
// FAST PATH
// ===========================================================================

__global__ __launch_bounds__(256) void k_cvtw(
    const float* __restrict__ whh_f, const float* __restrict__ whh_b,
    const float* __restrict__ wih_f, const float* __restrict__ wih_b,
    ushortT* __restrict__ whh16, ushortT* __restrict__ wih16)
{
    int idx = blockIdx.x * 256 + threadIdx.x;     // < 262144
    const float* s; ushortT* d;
    switch (blockIdx.y) {
        case 0: s = whh_f; d = whh16;            break;
        case 1: s = whh_b; d = whh16 + 262144;   break;
        case 2: s = wih_f; d = wih16;            break;
        default: s = wih_b; d = wih16 + 262144;  break;
    }
    d[idx] = f2bf(s[idx]);
}

__global__ __launch_bounds__(1024) void k_bias(
    const float* __restrict__ bih_f, const float* __restrict__ bhh_f,
    const float* __restrict__ bih_b, const float* __restrict__ bhh_b,
    float* __restrict__ biasc)
{
    int n = threadIdx.x;
    if (blockIdx.x == 0) biasc[n] = bih_f[n] + bhh_f[n];
    else                 biasc[1024 + n] = bih_b[n] + bhh_b[n];
}

// K-gin: gin[dirg][t][col*16 + row] = x_t @ Wih^T + bias  (bf16 MFMA)
//   WG = (group, t-tile, dir*2+half). half owns 512 gate-cols.
__global__
__attribute__((amdgpu_flat_work_group_size(512, 512)))
__attribute__((amdgpu_waves_per_eu(2, 2)))
void k_gin_mfma(
    const int* __restrict__ sent, const int* __restrict__ lens,
    const float* __restrict__ emb, const ushortT* __restrict__ wih16,
    const float* __restrict__ biasc, float* __restrict__ gin,
    int chunk_start, int CH)
{
    const int g = blockIdx.x, tsub = blockIdx.y;
    const int dir = blockIdx.z >> 1, half = blockIdx.z & 1;
    const int gmax = lens[g * 16];
    const int tt0 = tsub * 16;
    if (chunk_start + tt0 >= gmax) return;

    const int tid = threadIdx.x;
    const int w = tid >> 6, l = tid & 63, lr = l & 15, lg = l >> 4;

    __shared__ char x_raw[16 * 512];

    const int ucol = half * 128 + w * 16 + lr;
    short8 bfr[4][8];
    float bias_l[4];
    const ushortT* wsrc = wih16 + dir * 262144;
#pragma unroll
    for (int nt = 0; nt < 4; ++nt) {
        int col = nt * 256 + ucol;
        bias_l[nt] = biasc[dir * 1024 + col];
#pragma unroll
        for (int kt = 0; kt < 8; ++kt)
            bfr[nt][kt] = *(const short8*)(wsrc + (size_t)col * 256 + kt * 32 + lg * 8);
    }
#pragma unroll
    for (int nt = 0; nt < 4; ++nt) {
        PINV(bias_l[nt]);
#pragma unroll
        for (int kt = 0; kt < 8; ++kt) PINV(bfr[nt][kt]);
    }

    const int srow = tid >> 5, sseg = tid & 31;
    const int slen = lens[g * 16 + srow];
    const int sb = (g * 16 + srow) * 512;

    for (int i = 0; i < 16; ++i) {
        int tg = chunk_start + tt0 + i;
        if (tg >= gmax) break;

        int tsrc = dir ? (slen - 1 - tg) : tg;
        if (tsrc < 0) tsrc = 0;
        if (tsrc > 511) tsrc = 511;
        int tok = sent[sb + tsrc];
        const float* es = emb + (size_t)tok * 256 + sseg * 8;
        float4 e0 = *(const float4*)es;
        float4 e1 = *(const float4*)(es + 4);
        short8 xv;
        xv[0] = (short)f2bf(e0.x); xv[1] = (short)f2bf(e0.y);
        xv[2] = (short)f2bf(e0.z); xv[3] = (short)f2bf(e0.w);
        xv[4] = (short)f2bf(e1.x); xv[5] = (short)f2bf(e1.y);
        xv[6] = (short)f2bf(e1.z); xv[7] = (short)f2bf(e1.w);
        int sa = (srow * 512 + sseg * 16) ^ ((srow & 7) << 4);
        *(short8*)&x_raw[sa] = xv;
        __syncthreads();

        short8 af[8];
#pragma unroll
        for (int kt = 0; kt < 8; ++kt) {
            int a = (lr * 512 + kt * 64 + lg * 16) ^ ((lr & 7) << 4);
            af[kt] = *(const short8*)&x_raw[a];
        }
        f32x4 acc[4];
#pragma unroll
        for (int nt = 0; nt < 4; ++nt) {
            acc[nt][0] = bias_l[nt]; acc[nt][1] = bias_l[nt];
            acc[nt][2] = bias_l[nt]; acc[nt][3] = bias_l[nt];
        }
#pragma unroll
        for (int kt = 0; kt < 8; ++kt)
#pragma unroll
            for (int nt = 0; nt < 4; ++nt)
                acc[nt] = __builtin_amdgcn_mfma_f32_16x16x32_bf16(af[kt], bfr[nt][kt], acc[nt], 0, 0, 0);

        float* ginp = gin + ((size_t)((dir * 4 + g) * CH + (tt0 + i))) * 16384;
#pragma unroll
        for (int nt = 0; nt < 4; ++nt)
            *(f32x4*)(ginp + (nt * 256 + ucol) * 16 + lg * 4) = acc[nt];
        __syncthreads();
    }
}

// K-rec: 2 CUs per (group,dir) with SLIM mailbox: publish own h values from
//   registers (agent-scope), all-lane spin -> only 2 barriers per step.
__global__
__attribute__((amdgpu_flat_work_group_size(512, 512)))
__attribute__((amdgpu_waves_per_eu(2, 2)))
void k_rec_mfma(
    const int* __restrict__ lens, const ushortT* __restrict__ whh16,
    const float* __restrict__ gin, ushortT* __restrict__ hout,
    ushortT* __restrict__ st_h, float* __restrict__ st_c,
    unsigned int* __restrict__ hexu, unsigned int* __restrict__ flags,
    int chunk_start, int CH)
{
    const int g = blockIdx.x, dir = blockIdx.y, half = blockIdx.z;
    const int gmax = lens[g * 16];
    const int nsteps = min(CH, gmax - chunk_start);
    if (nsteps <= 0) return;

    const int tid = threadIdx.x;
    const int w = tid >> 6, l = tid & 63, lr = l & 15, lg = l >> 4;
    const int dirg = dir * 4 + g;

    __shared__ char h_s[2][8192];   // [buf][row*512B + unit*2B], XOR-swizzled

    int lenr[4];
#pragma unroll
    for (int r = 0; r < 4; ++r) lenr[r] = lens[g * 16 + lg * 4 + r];

    // weights for this lane's unit column (4 gates x 8 k-tiles); plain loads
    // (round-5 proven: compiler streams them from L2, well overlapped)
    const int ucol = half * 128 + w * 16 + lr;
    short8 bfr[4][8];
    {
        const ushortT* wsrc = whh16 + dir * 262144;
#pragma unroll
        for (int nt = 0; nt < 4; ++nt) {
            const ushortT* wp = wsrc + (size_t)(nt * 256 + ucol) * 256 + lg * 8;
#pragma unroll
            for (int kt = 0; kt < 8; ++kt)
                bfr[nt][kt] = *(const short8*)(wp + kt * 32);
        }
    }

    // state init / restore
    float c[4];
    if (chunk_start == 0) {
#pragma unroll
        for (int r = 0; r < 4; ++r) c[r] = 0.0f;
        for (int i = tid; i < 2048; i += 512) ((int*)h_s[0])[i] = 0;
    } else {
        const float* cs = st_c + ((size_t)(dirg * 2 + half)) * 2048 + tid * 4;
#pragma unroll
        for (int r = 0; r < 4; ++r) c[r] = cs[r];
        const int* hs = (const int*)st_h + dirg * 2048;
        for (int i = tid; i < 2048; i += 512) ((int*)h_s[0])[i] = hs[i];
    }
    __syncthreads();

    // mailbox: exu = 2 slots x 2048 uints per dirg; uint = 2 packed bf16 rows
    unsigned int* exu = hexu + dirg * 4096;
    unsigned int* flagMe = flags + dirg * 2 + half;
    unsigned int* flagPeer = flags + dirg * 2 + (half ^ 1);

    // publish index: lane owns col ucol, rows lg*4+{0..3} -> 2 uints
    const int pub_base = ucol * 8 + lg * 2;

    // peer-fetch constants: i = tid*2+s2 -> peer col + row-pair
    int pf_uidx[2], pf_lds0[2], pf_lds1[2];
#pragma unroll
    for (int s2 = 0; s2 < 2; ++s2) {
        int i = tid * 2 + s2;
        int pcol = ((half ^ 1) << 7) + (i >> 3);
        int sub = i & 7;
        pf_uidx[s2] = pcol * 8 + sub;
        int r0 = (sub >> 1) * 4 + (sub & 1) * 2;
        pf_lds0[s2] = (r0 * 512 + pcol * 2) ^ ((r0 & 7) << 4);
        int r1 = r0 + 1;
        pf_lds1[s2] = (r1 * 512 + pcol * 2) ^ ((r1 & 7) << 4);
    }

    const float* ginp = gin + (size_t)dirg * CH * 16384;
    int p = 0;
    for (int tt = 0; tt < nsteps; ++tt) {
        const int t_glob = chunk_start + tt;

        // gin (input projection) for my 4 gate-cols; consumed in pointwise
        f32x4 gv[4];
#pragma unroll
        for (int nt = 0; nt < 4; ++nt)
            gv[nt] = *(const f32x4*)(ginp + (size_t)tt * 16384 + (nt * 256 + ucol) * 16 + lg * 4);

        // h @ Whh^T
        const char* hb = h_s[p];
        f32x4 acc[4];
#pragma unroll
        for (int nt = 0; nt < 4; ++nt) { acc[nt][0] = 0.f; acc[nt][1] = 0.f; acc[nt][2] = 0.f; acc[nt][3] = 0.f; }
#pragma unroll
        for (int kt = 0; kt < 8; ++kt) {
            int a_ = (lr * 512 + kt * 64 + lg * 16) ^ ((lr & 7) << 4);
            short8 af = *(const short8*)&hb[a_];
#pragma unroll
            for (int nt = 0; nt < 4; ++nt)
                acc[nt] = __builtin_amdgcn_mfma_f32_16x16x32_bf16(af, bfr[nt][kt], acc[nt], 0, 0, 0);
        }

        // pointwise cell; write own LDS; publish own values from REGISTERS
        char* hw = h_s[p ^ 1];
        unsigned int* exs = exu + ((t_glob + 1) & 1) * 2048;
        ushortT hh[4];
#pragma unroll
        for (int r = 0; r < 4; ++r) {
            float i_ = acc[0][r] + gv[0][r];
            float f_ = acc[1][r] + gv[1][r];
            float g_ = acc[2][r] + gv[2][r];
            float o_ = acc[3][r] + gv[3][r];
            float cn = fsig(f_) * c[r] + fsig(i_) * ftanh(g_);
            float hn = fsig(o_) * ftanh(cn);
            c[r] = cn;
            hh[r] = f2bf(hn);
            int row = lg * 4 + r;
            *(ushortT*)&hw[(row * 512 + ucol * 2) ^ ((row & 7) << 4)] = hh[r];
        }
        unsigned int v01 = (unsigned int)hh[0] | ((unsigned int)hh[1] << 16);
        unsigned int v23 = (unsigned int)hh[2] | ((unsigned int)hh[3] << 16);
        __hip_atomic_store(&exs[pub_base + 0], v01, __ATOMIC_RELAXED, __HIP_MEMORY_SCOPE_AGENT);
        __hip_atomic_store(&exs[pub_base + 1], v23, __ATOMIC_RELAXED, __HIP_MEMORY_SCOPE_AGENT);
#pragma unroll
        for (int r = 0; r < 4; ++r) {
            if (t_glob < lenr[r]) {
                int row = lg * 4 + r;
                int tp = dir ? (lenr[r] - 1 - t_glob) : t_glob;
                hout[((size_t)((g * 16 + row) * 512 + tp)) * 512 + dir * 256 + ucol] = hh[r];
            }
        }

        __syncthreads();   // drains vmcnt: publishes acked at LLC; LDS visible

        if (tid == 0)
            __hip_atomic_store(flagMe, (unsigned int)(t_glob + 1), __ATOMIC_RELEASE, __HIP_MEMORY_SCOPE_AGENT);

        {   // all-lane spin (wave-coalesced, same address)
            unsigned int tgt = (unsigned int)(t_glob + 1);
            int guard = 0;
            while (__hip_atomic_load(flagPeer, __ATOMIC_RELAXED, __HIP_MEMORY_SCOPE_AGENT) < tgt
                   && ++guard < (1 << 16)) {}
        }

        // fetch peer half into LDS
#pragma unroll
        for (int s2 = 0; s2 < 2; ++s2) {
            unsigned int v = __hip_atomic_load(&exs[pf_uidx[s2]], __ATOMIC_RELAXED, __HIP_MEMORY_SCOPE_AGENT);
            *(ushortT*)&hw[pf_lds0[s2]] = (ushortT)(v & 0xffffu);
            *(ushortT*)&hw[pf_lds1[s2]] = (ushortT)(v >> 16);
        }
        __syncthreads();
        p ^= 1;
    }

    // save state
    float* cs = st_c + ((size_t)(dirg * 2 + half)) * 2048 + tid * 4;
#pragma unroll
    for (int r = 0; r < 4; ++r) cs[r] = c[r];
    if (half == 0) {
        int* hs = (int*)st_h + dirg * 2048;
        for (int i = tid; i < 2048; i += 512) hs[i] = ((int*)h_s[p])[i];
    }
}

// K-scores: scores[b,t,:] = h[b,t,:] (bf16) @ w_out^T + b_out  (t < len)
__global__ __launch_bounds__(256) void k_scores_bf(
    const int* __restrict__ lens, const ushortT* __restrict__ hout,
    const float* __restrict__ w_out, const float* __restrict__ b_out,
    float* __restrict__ scores)
{
    const int b = blockIdx.y;
    const int t0 = blockIdx.x * 32;
    const int len = lens[b];
    if (t0 >= len) return;

    __shared__ float w_s[20 * 513];
    __shared__ float row_s[512];
    __shared__ float part_s[20][9];
    __shared__ float bo_s[20];

    const int tid = threadIdx.x;
    for (int e = tid; e < 20 * 512; e += 256) w_s[(e >> 9) * 513 + (e & 511)] = w_out[e];
    if (tid < 20) bo_s[tid] = b_out[tid];
    __syncthreads();

    const int tend = min(t0 + 32, len);
    const int tag = tid >> 3, sl = tid & 7;
    for (int t = t0; t < tend; ++t) {
        const ushortT* hr = hout + ((size_t)(b * 512 + t)) * 512;
        unsigned int v = ((const unsigned int*)hr)[tid];
        row_s[tid * 2] = bf2f(v & 0xffffu);
        row_s[tid * 2 + 1] = bf2f(v >> 16);
        __syncthreads();
        if (tid < 160) {
            float s = 0.0f;
#pragma unroll 8
            for (int j = 0; j < 64; ++j) {
                int k = sl + (((j + tag) & 63) << 3);
                s = fmaf(w_s[tag * 513 + k], row_s[k], s);
            }
            part_s[tag][sl] = s;
        }
        __syncthreads();
        if (tid < 20) {
            float s = bo_s[tid];
#pragma unroll
            for (int j = 0; j < 8; ++j) s += part_s[tid][j];
            scores[((size_t)(b * 512 + t)) * 20 + tid] = s;
        }
        __syncthreads();
    }
}

__global__ __launch_bounds__(64) void k_viterbi_s(
    const int* __restrict__ lens, const float* __restrict__ scores,
    const float* __restrict__ trans, float* __restrict__ out)
{
    const int b = blockIdx.x;
    const int lane = threadIdx.x;
    const int len = lens[b];

    __shared__ float tr_s[20][21];
    __shared__ float fv_s[20];
    __shared__ float term_s[20];
    __shared__ unsigned char bp_s[512][20];
    __shared__ unsigned char path_s[512];

    for (int e = lane; e < 400; e += 64) tr_s[e / 20][e % 20] = trans[e];
    if (lane < 20) fv_s[lane] = (lane == TAG_START) ? 0.0f : NEGV;
    __syncthreads();

    const float* sc = scores + ((size_t)(b << 9)) * 20;
    for (int t = 0; t < len; ++t) {
        float m = 0.0f; int arg = 0;
        if (lane < 20) {
            m = fv_s[0] + tr_s[lane][0]; arg = 0;
#pragma unroll
            for (int k = 1; k < 20; ++k) {
                float v = fv_s[k] + tr_s[lane][k];
                if (v > m) { m = v; arg = k; }
            }
            m += sc[t * 20 + lane];
        }
        __syncthreads();
        if (lane < 20) { fv_s[lane] = m; bp_s[t][lane] = (unsigned char)arg; }
        __syncthreads();
    }

    if (lane < 20) term_s[lane] = fv_s[lane] + tr_s[TAG_STOP][lane];
    __syncthreads();

    if (lane == 0) {
        float m = term_s[0]; int arg = 0;
        for (int k = 1; k < 20; ++k) if (term_s[k] > m) { m = term_s[k]; arg = k; }
        out[b] = m;
        int cur = arg;
        path_s[len - 1] = (unsigned char)cur;
        for (int j = len - 1; j >= 1; --j) {
            cur = bp_s[j][cur];
            path_s[j - 1] = (unsigned char)cur;
        }
    }
    __syncthreads();

    float* po = out + NB + ((size_t)b << 9);
    for (int p = lane; p < NL; p += 64) po[p] = (p < len) ? (float)path_s[p] : 0.0f;
}

// ===========================================================================
// FALLBACK PATH (round-2 proven)
// ===========================================================================
__global__ __launch_bounds__(256) void k_transpose_fb(
    const float* __restrict__ whh_f, const float* __restrict__ whh_b,
    const float* __restrict__ wih_f, const float* __restrict__ wih_b,
    float* __restrict__ thh_f, float* __restrict__ thh_b,
    float* __restrict__ tih_f, float* __restrict__ tih_b)
{
    int e = blockIdx.x * 256 + threadIdx.x;
    const float* wm; float* wt;
    switch (blockIdx.y) {
        case 0: wm = whh_f; wt = thh_f; break;
        case 1: wm = whh_b; wt = thh_b; break;
        case 2: wm = wih_f; wt = tih_f; break;
        default: wm = wih_b; wt = tih_b; break;
    }
    int n = e >> 8, k = e & 255;
    wt[k * 1024 + n] = wm[e];
}

__global__ __launch_bounds__(1024) void k_rec_fb(
    const int* __restrict__ sent, const int* __restrict__ lens,
    const float* __restrict__ emb,
    const float* __restrict__ thh_f, const float* __restrict__ thh_b,
    const float* __restrict__ tih_f, const float* __restrict__ tih_b,
    const float* __restrict__ b_ih_f, const float* __restrict__ b_hh_f,
    const float* __restrict__ b_ih_b, const float* __restrict__ b_hh_b,
    const float* __restrict__ w_out,
    float* __restrict__ sc_f, float* __restrict__ sc_b)
{
    const int b = blockIdx.x, dir = blockIdx.y;
    const int len = lens[b];
    const int n = threadIdx.x;
    const float* Whh = dir ? thh_b : thh_f;
    const float* Wih = dir ? tih_b : tih_f;
    const float* bi = dir ? b_ih_b : b_ih_f;
    const float* bh = dir ? b_hh_b : b_hh_f;
    float* scout = dir ? sc_b : sc_f;

    __shared__ float x_s[256];
    __shared__ float h_s[256];
    __shared__ float g_s[1024];
    __shared__ float bias_s[1024];
    __shared__ float wout_s[20 * 257];
    __shared__ float part_s[20][8];

    bias_s[n] = bi[n] + bh[n];
    for (int e = n; e < 20 * 256; e += 1024)
        wout_s[(e >> 8) * 257 + (e & 255)] = w_out[(e >> 8) * 512 + dir * 256 + (e & 255)];
    if (n < 256) h_s[n] = 0.0f;
    float c = 0.0f;
    __syncthreads();

    const int sbase = b << 9;
    for (int t = 0; t < len; ++t) {
        if (n < 256) {
            int ti = dir ? (len - 1 - t) : t;
            int tok = sent[sbase + ti];
            x_s[n] = emb[(size_t)tok * NE + n];
        }
        __syncthreads();
        float acc = bias_s[n];
        const float* wi = Wih + n;
        const float* wh = Whh + n;
#pragma unroll 8
        for (int k = 0; k < 256; ++k) {
            acc = fmaf(wh[(size_t)(k << 10)], h_s[k], acc);
            acc = fmaf(wi[(size_t)(k << 10)], x_s[k], acc);
        }
        g_s[n] = acc;
        __syncthreads();
        if (n < 256) {
            float ig = g_s[n], fg = g_s[n + 256], gg = g_s[n + 512], og = g_s[n + 768];
            float cn = sigf_slow(fg) * c + sigf_slow(ig) * tanhf(gg);
            float hn = sigf_slow(og) * tanhf(cn);
            c = cn; h_s[n] = hn;
        }
        __syncthreads();
        if (n < 160) {
            const int tag = n >> 3, sl = n & 7;
            const float* wrow = wout_s + tag * 257;
            float s = 0.0f;
#pragma unroll 8
            for (int j = 0; j < 32; ++j) { int k = sl + (j << 3); s = fmaf(wrow[k], h_s[k], s); }
            part_s[tag][sl] = s;
        }
        __syncthreads();
        if (n < 20) {
            float s = part_s[n][0];
#pragma unroll
            for (int j = 1; j < 8; ++j) s += part_s[n][j];
            int tp = dir ? (len - 1 - t) : t;
            scout[(size_t)(sbase + tp) * 20 + n] = s;
        }
    }
}

__global__ __launch_bounds__(64) void k_viterbi_fb(
    const int* __restrict__ lens,
    const float* __restrict__ sc_f, const float* __restrict__ sc_b,
    const float* __restrict__ b_out, const float* __restrict__ trans,
    float* __restrict__ out)
{
    const int b = blockIdx.x;
    const int lane = threadIdx.x;
    const int len = lens[b];

    __shared__ float tr_s[20][21];
    __shared__ float fv_s[20];
    __shared__ float term_s[20];
    __shared__ float bo_s[20];
    __shared__ unsigned char bp_s[512][20];
    __shared__ unsigned char path_s[512];

    for (int e = lane; e < 400; e += 64) tr_s[e / 20][e % 20] = trans[e];
    if (lane < 20) { fv_s[lane] = (lane == TAG_START) ? 0.0f : NEGV; bo_s[lane] = b_out[lane]; }
    __syncthreads();

    const size_t sb = (size_t)(b << 9) * 20;
    for (int t = 0; t < len; ++t) {
        float m = 0.0f; int arg = 0;
        if (lane < 20) {
            m = fv_s[0] + tr_s[lane][0]; arg = 0;
#pragma unroll
            for (int k = 1; k < 20; ++k) {
                float v = fv_s[k] + tr_s[lane][k];
                if (v > m) { m = v; arg = k; }
            }
            m += sc_f[sb + t * 20 + lane] + sc_b[sb + t * 20 + lane] + bo_s[lane];
        }
        __syncthreads();
        if (lane < 20) { fv_s[lane] = m; bp_s[t][lane] = (unsigned char)arg; }
        __syncthreads();
    }
    if (lane < 20) term_s[lane] = fv_s[lane] + tr_s[TAG_STOP][lane];
    __syncthreads();
    if (lane == 0) {
        float m = term_s[0]; int arg = 0;
        for (int k = 1; k < 20; ++k) if (term_s[k] > m) { m = term_s[k]; arg = k; }
        out[b] = m;
        int cur = arg;
        path_s[len - 1] = (unsigned char)cur;
        for (int j = len - 1; j >= 1; --j) { cur = bp_s[j][cur]; path_s[j - 1] = (unsigned char)cur; }
    }
    __syncthreads();
    float* po = out + NB + ((size_t)b << 9);
    for (int p = lane; p < NL; p += 64) po[p] = (p < len) ? (float)path_s[p] : 0.0f;
}

// ===========================================================================
extern "C" void kernel_launch(void* const* d_in, const int* in_sizes, int n_in,
                              void* d_out, int out_size, void* d_ws, size_t ws_size,
                              hipStream_t stream)
{
    const int*   sent   = (const int*)d_in[0];
    const int*   lens   = (const int*)d_in[1];
    const float* emb    = (const float*)d_in[2];
    const float* w_ih_f = (const float*)d_in[3];
    const float* w_hh_f = (const float*)d_in[4];
    const float* b_ih_f = (const float*)d_in[5];
    const float* b_hh_f = (const float*)d_in[6];
    const float* w_ih_b = (const float*)d_in[7];
    const float* w_hh_b = (const float*)d_in[8];
    const float* b_ih_b = (const float*)d_in[9];
    const float* b_hh_b = (const float*)d_in[10];
    const float* w_out  = (const float*)d_in[11];
    const float* b_out  = (const float*)d_in[12];
    const float* trans  = (const float*)d_in[13];
    float* out = (float*)d_out;

    char* w = (char*)d_ws;
    // layout:
    //  whh16   @ 0        (1 MB)     wih16 @ 1048576 (1 MB)
    //  biasc   @ 2097152  (8 KB)     st_h  @ 2105344 (64 KB)
    //  st_c    @ 2170880  (128 KB)   hex   @ 2301952 (128 KB)
    //  flags   @ 2433024  (4 KB)     scores@ 2437120 (2.5 MB)
    //  hout    @ 5058560  (32 MB)    gin   @ 38612992 (CH*512 KB)
    const size_t base = 38612992;
    int CH = 0;
    const int chs[6] = {512, 256, 192, 128, 64, 32};
    for (int i = 0; i < 6; ++i)
        if (base + (size_t)chs[i] * 524288 <= ws_size) { CH = chs[i]; break; }

    if (CH) {
        ushortT* whh16 = (ushortT*)(w);
        ushortT* wih16 = (ushortT*)(w + 1048576);
        float*   biasc = (float*)(w + 2097152);
        ushortT* st_h  = (ushortT*)(w + 2105344);
        float*   st_c  = (float*)(w + 2170880);
        unsigned int* hexu = (unsigned int*)(w + 2301952);
        unsigned int* flags = (unsigned int*)(w + 2433024);
        float*   scores= (float*)(w + 2437120);
        ushortT* hout  = (ushortT*)(w + 5058560);
        float*   gin   = (float*)(w + base);

        hipMemsetAsync(flags, 0, 4096, stream);
        k_cvtw<<<dim3(1024, 4), 256, 0, stream>>>(w_hh_f, w_hh_b, w_ih_f, w_ih_b, whh16, wih16);
        k_bias<<<2, 1024, 0, stream>>>(b_ih_f, b_hh_f, b_ih_b, b_hh_b, biasc);

        for (int cs = 0; cs < NL; cs += CH) {
            k_gin_mfma<<<dim3(4, CH / 16, 4), 512, 0, stream>>>(
                sent, lens, emb, wih16, biasc, gin, cs, CH);
            k_rec_mfma<<<dim3(4, 2, 2), 512, 0, stream>>>(
                lens, whh16, gin, hout, st_h, st_c, hexu, flags, cs, CH);
        }
        k_scores_bf<<<dim3(16, 64), 256, 0, stream>>>(lens, hout, w_out, b_out, scores);
        k_viterbi_s<<<64, 64, 0, stream>>>(lens, scores, trans, out);
    } else {
        float* ws2   = (float*)d_ws;
        float* thh_f = ws2;
        float* thh_b = thh_f + 262144;
        float* tih_f = thh_b + 262144;
        float* tih_b = tih_f + 262144;
        float* sc_f  = tih_b + 262144;
        float* sc_b  = sc_f + (size_t)NB * NL * NT;

        k_transpose_fb<<<dim3(1024, 4), 256, 0, stream>>>(
            w_hh_f, w_hh_b, w_ih_f, w_ih_b, thh_f, thh_b, tih_f, tih_b);
        k_rec_fb<<<dim3(NB, 2), 1024, 0, stream>>>(
            sent, lens, emb, thh_f, thh_b, tih_f, tih_b,
            b_ih_f, b_hh_f, b_ih_b, b_hh_b, w_out, sc_f, sc_b);
        k_viterbi_fb<<<NB, 64, 0, stream>>>(lens, sc_f, sc_b, b_out, trans, out);
    }
}

// Round 10
// 2175.641 us; speedup vs baseline: 1.8078x; 1.1029x over previous
//
#include <hip/hip_runtime.h>
#include <hip/hip_bf16.h>
#include <math.h>

#define NV 50000
#define NE 256
#define NH 256
#define NT 20
#define NB 64
#define NL 512
#define TAG_START 18
#define TAG_STOP 19
#define NEGV -10000.0f

typedef unsigned short ushortT;
typedef __attribute__((ext_vector_type(4))) float f32x4;
typedef __attribute__((ext_vector_type(8))) short short8;

#define PINV(x) asm volatile("" : "+v"(x))

__device__ __forceinline__ float sigf_slow(float x) { return 1.0f / (1.0f + expf(-x)); }
__device__ __forceinline__ float fsig(float x) { return 1.0f / (1.0f + __expf(-x)); }
__device__ __forceinline__ float ftanh(float x) { return 1.0f - 2.0f / (1.0f + __expf(2.0f * x)); }
__device__ __forceinline__ ushortT f2bf(float f) {
    unsigned int u = __float_as_uint(f);
    u += 0x7fffu + ((u >> 16) & 1u);
    return (ushortT)(u >> 16);
}
__device__ __forceinline__ float bf2f(unsigned int bits16) {
    return __uint_as_float(bits16 << 16);
}

// ===========================================================================
// FAST PATH
// ===========================================================================

__global__ __launch_bounds__(256) void k_cvtw(
    const float* __restrict__ whh_f, const float* __restrict__ whh_b,
    const float* __restrict__ wih_f, const float* __restrict__ wih_b,
    ushortT* __restrict__ whh16, ushortT* __restrict__ wih16)
{
    int idx = blockIdx.x * 256 + threadIdx.x;     // < 262144
    const float* s; ushortT* d;
    switch (blockIdx.y) {
        case 0: s = whh_f; d = whh16;            break;
        case 1: s = whh_b; d = whh16 + 262144;   break;
        case 2: s = wih_f; d = wih16;            break;
        default: s = wih_b; d = wih16 + 262144;  break;
    }
    d[idx] = f2bf(s[idx]);
}

__global__ __launch_bounds__(1024) void k_bias(
    const float* __restrict__ bih_f, const float* __restrict__ bhh_f,
    const float* __restrict__ bih_b, const float* __restrict__ bhh_b,
    float* __restrict__ biasc)
{
    int n = threadIdx.x;
    if (blockIdx.x == 0) biasc[n] = bih_f[n] + bhh_f[n];
    else                 biasc[1024 + n] = bih_b[n] + bhh_b[n];
}

// K-gin: gin[dirg][t][col*16 + row] = x_t @ Wih^T + bias  (bf16 MFMA)
//   WG = (group, t-tile, dir*2+half). half owns 512 gate-cols.
__global__
__attribute__((amdgpu_flat_work_group_size(512, 512)))
__attribute__((amdgpu_waves_per_eu(2, 2)))
void k_gin_mfma(
    const int* __restrict__ sent, const int* __restrict__ lens,
    const float* __restrict__ emb, const ushortT* __restrict__ wih16,
    const float* __restrict__ biasc, float* __restrict__ gin,
    int chunk_start, int CH)
{
    const int g = blockIdx.x, tsub = blockIdx.y;
    const int dir = blockIdx.z >> 1, half = blockIdx.z & 1;
    const int gmax = lens[g * 16];
    const int tt0 = tsub * 16;
    if (chunk_start + tt0 >= gmax) return;

    const int tid = threadIdx.x;
    const int w = tid >> 6, l = tid & 63, lr = l & 15, lg = l >> 4;

    __shared__ char x_raw[16 * 512];

    const int ucol = half * 128 + w * 16 + lr;
    short8 bfr[4][8];
    float bias_l[4];
    const ushortT* wsrc = wih16 + dir * 262144;
#pragma unroll
    for (int nt = 0; nt < 4; ++nt) {
        int col = nt * 256 + ucol;
        bias_l[nt] = biasc[dir * 1024 + col];
#pragma unroll
        for (int kt = 0; kt < 8; ++kt)
            bfr[nt][kt] = *(const short8*)(wsrc + (size_t)col * 256 + kt * 32 + lg * 8);
    }
#pragma unroll
    for (int nt = 0; nt < 4; ++nt) {
        PINV(bias_l[nt]);
#pragma unroll
        for (int kt = 0; kt < 8; ++kt) PINV(bfr[nt][kt]);
    }

    const int srow = tid >> 5, sseg = tid & 31;
    const int slen = lens[g * 16 + srow];
    const int sb = (g * 16 + srow) * 512;

    for (int i = 0; i < 16; ++i) {
        int tg = chunk_start + tt0 + i;
        if (tg >= gmax) break;

        int tsrc = dir ? (slen - 1 - tg) : tg;
        if (tsrc < 0) tsrc = 0;
        if (tsrc > 511) tsrc = 511;
        int tok = sent[sb + tsrc];
        const float* es = emb + (size_t)tok * 256 + sseg * 8;
        float4 e0 = *(const float4*)es;
        float4 e1 = *(const float4*)(es + 4);
        short8 xv;
        xv[0] = (short)f2bf(e0.x); xv[1] = (short)f2bf(e0.y);
        xv[2] = (short)f2bf(e0.z); xv[3] = (short)f2bf(e0.w);
        xv[4] = (short)f2bf(e1.x); xv[5] = (short)f2bf(e1.y);
        xv[6] = (short)f2bf(e1.z); xv[7] = (short)f2bf(e1.w);
        int sa = (srow * 512 + sseg * 16) ^ ((srow & 7) << 4);
        *(short8*)&x_raw[sa] = xv;
        __syncthreads();

        short8 af[8];
#pragma unroll
        for (int kt = 0; kt < 8; ++kt) {
            int a = (lr * 512 + kt * 64 + lg * 16) ^ ((lr & 7) << 4);
            af[kt] = *(const short8*)&x_raw[a];
        }
        f32x4 acc[4];
#pragma unroll
        for (int nt = 0; nt < 4; ++nt) {
            acc[nt][0] = bias_l[nt]; acc[nt][1] = bias_l[nt];
            acc[nt][2] = bias_l[nt]; acc[nt][3] = bias_l[nt];
        }
#pragma unroll
        for (int kt = 0; kt < 8; ++kt)
#pragma unroll
            for (int nt = 0; nt < 4; ++nt)
                acc[nt] = __builtin_amdgcn_mfma_f32_16x16x32_bf16(af[kt], bfr[nt][kt], acc[nt], 0, 0, 0);

        float* ginp = gin + ((size_t)((dir * 4 + g) * CH + (tt0 + i))) * 16384;
#pragma unroll
        for (int nt = 0; nt < 4; ++nt)
            *(f32x4*)(ginp + (nt * 256 + ucol) * 16 + lg * 4) = acc[nt];
        __syncthreads();
    }
}

// K-rec: 2 CUs per (group,dir), SAME-XCD pairing via flat grid of 16:
//   bid and bid+8 round-robin to the same XCD -> mailbox runs at L2 speed.
//   Publish from registers; hout stores overlap the spin.
__global__
__attribute__((amdgpu_flat_work_group_size(512, 512)))
__attribute__((amdgpu_waves_per_eu(2, 2)))
void k_rec_mfma(
    const int* __restrict__ lens, const ushortT* __restrict__ whh16,
    const float* __restrict__ gin, ushortT* __restrict__ hout,
    ushortT* __restrict__ st_h, float* __restrict__ st_c,
    unsigned int* __restrict__ hexu, unsigned int* __restrict__ flags,
    int chunk_start, int CH)
{
    const int bid = blockIdx.x;
    const int half = bid >> 3;          // pair members differ by 8 in bid
    const int dirg = bid & 7;           // -> same XCD under mod-8 round-robin
    const int g = dirg & 3, dir = dirg >> 2;
    const int gmax = lens[g * 16];
    const int nsteps = min(CH, gmax - chunk_start);
    if (nsteps <= 0) return;

    const int tid = threadIdx.x;
    const int w = tid >> 6, l = tid & 63, lr = l & 15, lg = l >> 4;

    __shared__ char h_s[2][8192];   // [buf][row*512B + unit*2B], XOR-swizzled

    int lenr[4];
#pragma unroll
    for (int r = 0; r < 4; ++r) lenr[r] = lens[g * 16 + lg * 4 + r];

    // weights for this lane's unit column (4 gates x 8 k-tiles); plain loads
    const int ucol = half * 128 + w * 16 + lr;
    short8 bfr[4][8];
    {
        const ushortT* wsrc = whh16 + dir * 262144;
#pragma unroll
        for (int nt = 0; nt < 4; ++nt) {
            const ushortT* wp = wsrc + (size_t)(nt * 256 + ucol) * 256 + lg * 8;
#pragma unroll
            for (int kt = 0; kt < 8; ++kt)
                bfr[nt][kt] = *(const short8*)(wp + kt * 32);
        }
    }

    // state init / restore
    float c[4];
    if (chunk_start == 0) {
#pragma unroll
        for (int r = 0; r < 4; ++r) c[r] = 0.0f;
        for (int i = tid; i < 2048; i += 512) ((int*)h_s[0])[i] = 0;
    } else {
        const float* cs = st_c + ((size_t)(dirg * 2 + half)) * 2048 + tid * 4;
#pragma unroll
        for (int r = 0; r < 4; ++r) c[r] = cs[r];
        const int* hs = (const int*)st_h + dirg * 2048;
        for (int i = tid; i < 2048; i += 512) ((int*)h_s[0])[i] = hs[i];
    }
    __syncthreads();

    // mailbox: exu = 2 slots x 2048 uints per dirg; flags on separate lines
    unsigned int* exu = hexu + dirg * 4096;
    unsigned int* flagMe = flags + dirg * 32 + half * 16;
    unsigned int* flagPeer = flags + dirg * 32 + (half ^ 1) * 16;

    const int pub_base = ucol * 8 + lg * 2;

    int pf_uidx[2], pf_lds0[2], pf_lds1[2];
#pragma unroll
    for (int s2 = 0; s2 < 2; ++s2) {
        int i = tid * 2 + s2;
        int pcol = ((half ^ 1) << 7) + (i >> 3);
        int sub = i & 7;
        pf_uidx[s2] = pcol * 8 + sub;
        int r0 = (sub >> 1) * 4 + (sub & 1) * 2;
        pf_lds0[s2] = (r0 * 512 + pcol * 2) ^ ((r0 & 7) << 4);
        int r1 = r0 + 1;
        pf_lds1[s2] = (r1 * 512 + pcol * 2) ^ ((r1 & 7) << 4);
    }

    const float* ginp = gin + (size_t)dirg * CH * 16384;
    int p = 0;
    for (int tt = 0; tt < nsteps; ++tt) {
        const int t_glob = chunk_start + tt;

        f32x4 gv[4];
#pragma unroll
        for (int nt = 0; nt < 4; ++nt)
            gv[nt] = *(const f32x4*)(ginp + (size_t)tt * 16384 + (nt * 256 + ucol) * 16 + lg * 4);

        const char* hb = h_s[p];
        f32x4 acc[4];
#pragma unroll
        for (int nt = 0; nt < 4; ++nt) { acc[nt][0] = 0.f; acc[nt][1] = 0.f; acc[nt][2] = 0.f; acc[nt][3] = 0.f; }
#pragma unroll
        for (int kt = 0; kt < 8; ++kt) {
            int a_ = (lr * 512 + kt * 64 + lg * 16) ^ ((lr & 7) << 4);
            short8 af = *(const short8*)&hb[a_];
#pragma unroll
            for (int nt = 0; nt < 4; ++nt)
                acc[nt] = __builtin_amdgcn_mfma_f32_16x16x32_bf16(af, bfr[nt][kt], acc[nt], 0, 0, 0);
        }

        // pointwise; write own LDS; publish from registers
        char* hw = h_s[p ^ 1];
        unsigned int* exs = exu + ((t_glob + 1) & 1) * 2048;
        ushortT hh[4];
#pragma unroll
        for (int r = 0; r < 4; ++r) {
            float i_ = acc[0][r] + gv[0][r];
            float f_ = acc[1][r] + gv[1][r];
            float g_ = acc[2][r] + gv[2][r];
            float o_ = acc[3][r] + gv[3][r];
            float cn = fsig(f_) * c[r] + fsig(i_) * ftanh(g_);
            float hn = fsig(o_) * ftanh(cn);
            c[r] = cn;
            hh[r] = f2bf(hn);
            int row = lg * 4 + r;
            *(ushortT*)&hw[(row * 512 + ucol * 2) ^ ((row & 7) << 4)] = hh[r];
        }
        unsigned int v01 = (unsigned int)hh[0] | ((unsigned int)hh[1] << 16);
        unsigned int v23 = (unsigned int)hh[2] | ((unsigned int)hh[3] << 16);
        __hip_atomic_store(&exs[pub_base + 0], v01, __ATOMIC_RELAXED, __HIP_MEMORY_SCOPE_AGENT);
        __hip_atomic_store(&exs[pub_base + 1], v23, __ATOMIC_RELAXED, __HIP_MEMORY_SCOPE_AGENT);

        __syncthreads();   // drains vmcnt: all lanes' publishes visible

        if (tid == 0)
            __hip_atomic_store(flagMe, (unsigned int)(t_glob + 1), __ATOMIC_RELEASE, __HIP_MEMORY_SCOPE_AGENT);

        // hout stores overlap the spin window
#pragma unroll
        for (int r = 0; r < 4; ++r) {
            if (t_glob < lenr[r]) {
                int row = lg * 4 + r;
                int tp = dir ? (lenr[r] - 1 - t_glob) : t_glob;
                hout[((size_t)((g * 16 + row) * 512 + tp)) * 512 + dir * 256 + ucol] = hh[r];
            }
        }

        {   // all-lane spin (wave-coalesced, same address)
            unsigned int tgt = (unsigned int)(t_glob + 1);
            int guard = 0;
            while (__hip_atomic_load(flagPeer, __ATOMIC_RELAXED, __HIP_MEMORY_SCOPE_AGENT) < tgt
                   && ++guard < (1 << 16)) {}
        }

        // fetch peer half into LDS
#pragma unroll
        for (int s2 = 0; s2 < 2; ++s2) {
            unsigned int v = __hip_atomic_load(&exs[pf_uidx[s2]], __ATOMIC_RELAXED, __HIP_MEMORY_SCOPE_AGENT);
            *(ushortT*)&hw[pf_lds0[s2]] = (ushortT)(v & 0xffffu);
            *(ushortT*)&hw[pf_lds1[s2]] = (ushortT)(v >> 16);
        }
        __syncthreads();
        p ^= 1;
    }

    // save state
    float* cs = st_c + ((size_t)(dirg * 2 + half)) * 2048 + tid * 4;
#pragma unroll
    for (int r = 0; r < 4; ++r) cs[r] = c[r];
    if (half == 0) {
        int* hs = (int*)st_h + dirg * 2048;
        for (int i = tid; i < 2048; i += 512) hs[i] = ((int*)h_s[p])[i];
    }
}

// K-scores: scores[b,t,:] = h[b,t,:] (bf16) @ w_out^T + b_out  (t < len)
__global__ __launch_bounds__(256) void k_scores_bf(
    const int* __restrict__ lens, const ushortT* __restrict__ hout,
    const float* __restrict__ w_out, const float* __restrict__ b_out,
    float* __restrict__ scores)
{
    const int b = blockIdx.y;
    const int t0 = blockIdx.x * 32;
    const int len = lens[b];
    if (t0 >= len) return;

    __shared__ float w_s[20 * 513];
    __shared__ float row_s[512];
    __shared__ float part_s[20][9];
    __shared__ float bo_s[20];

    const int tid = threadIdx.x;
    for (int e = tid; e < 20 * 512; e += 256) w_s[(e >> 9) * 513 + (e & 511)] = w_out[e];
    if (tid < 20) bo_s[tid] = b_out[tid];
    __syncthreads();

    const int tend = min(t0 + 32, len);
    const int tag = tid >> 3, sl = tid & 7;
    for (int t = t0; t < tend; ++t) {
        const ushortT* hr = hout + ((size_t)(b * 512 + t)) * 512;
        unsigned int v = ((const unsigned int*)hr)[tid];
        row_s[tid * 2] = bf2f(v & 0xffffu);
        row_s[tid * 2 + 1] = bf2f(v >> 16);
        __syncthreads();
        if (tid < 160) {
            float s = 0.0f;
#pragma unroll 8
            for (int j = 0; j < 64; ++j) {
                int k = sl + (((j + tag) & 63) << 3);
                s = fmaf(w_s[tag * 513 + k], row_s[k], s);
            }
            part_s[tag][sl] = s;
        }
        __syncthreads();
        if (tid < 20) {
            float s = bo_s[tid];
#pragma unroll
            for (int j = 0; j < 8; ++j) s += part_s[tid][j];
            scores[((size_t)(b * 512 + t)) * 20 + tid] = s;
        }
        __syncthreads();
    }
}

__global__ __launch_bounds__(64) void k_viterbi_s(
    const int* __restrict__ lens, const float* __restrict__ scores,
    const float* __restrict__ trans, float* __restrict__ out)
{
    const int b = blockIdx.x;
    const int lane = threadIdx.x;
    const int len = lens[b];

    __shared__ float tr_s[20][21];
    __shared__ float fv_s[20];
    __shared__ float term_s[20];
    __shared__ unsigned char bp_s[512][20];
    __shared__ unsigned char path_s[512];

    for (int e = lane; e < 400; e += 64) tr_s[e / 20][e % 20] = trans[e];
    if (lane < 20) fv_s[lane] = (lane == TAG_START) ? 0.0f : NEGV;
    __syncthreads();

    const float* sc = scores + ((size_t)(b << 9)) * 20;
    for (int t = 0; t < len; ++t) {
        float m = 0.0f; int arg = 0;
        if (lane < 20) {
            m = fv_s[0] + tr_s[lane][0]; arg = 0;
#pragma unroll
            for (int k = 1; k < 20; ++k) {
                float v = fv_s[k] + tr_s[lane][k];
                if (v > m) { m = v; arg = k; }
            }
            m += sc[t * 20 + lane];
        }
        __syncthreads();
        if (lane < 20) { fv_s[lane] = m; bp_s[t][lane] = (unsigned char)arg; }
        __syncthreads();
    }

    if (lane < 20) term_s[lane] = fv_s[lane] + tr_s[TAG_STOP][lane];
    __syncthreads();

    if (lane == 0) {
        float m = term_s[0]; int arg = 0;
        for (int k = 1; k < 20; ++k) if (term_s[k] > m) { m = term_s[k]; arg = k; }
        out[b] = m;
        int cur = arg;
        path_s[len - 1] = (unsigned char)cur;
        for (int j = len - 1; j >= 1; --j) {
            cur = bp_s[j][cur];
            path_s[j - 1] = (unsigned char)cur;
        }
    }
    __syncthreads();

    float* po = out + NB + ((size_t)b << 9);
    for (int p = lane; p < NL; p += 64) po[p] = (p < len) ? (float)path_s[p] : 0.0f;
}

// ===========================================================================
// FALLBACK PATH (round-2 proven)
// ===========================================================================
__global__ __launch_bounds__(256) void k_transpose_fb(
    const float* __restrict__ whh_f, const float* __restrict__ whh_b,
    const float* __restrict__ wih_f, const float* __restrict__ wih_b,
    float* __restrict__ thh_f, float* __restrict__ thh_b,
    float* __restrict__ tih_f, float* __restrict__ tih_b)
{
    int e = blockIdx.x * 256 + threadIdx.x;
    const float* wm; float* wt;
    switch (blockIdx.y) {
        case 0: wm = whh_f; wt = thh_f; break;
        case 1: wm = whh_b; wt = thh_b; break;
        case 2: wm = wih_f; wt = tih_f; break;
        default: wm = wih_b; wt = tih_b; break;
    }
    int n = e >> 8, k = e & 255;
    wt[k * 1024 + n] = wm[e];
}

__global__ __launch_bounds__(1024) void k_rec_fb(
    const int* __restrict__ sent, const int* __restrict__ lens,
    const float* __restrict__ emb,
    const float* __restrict__ thh_f, const float* __restrict__ thh_b,
    const float* __restrict__ tih_f, const float* __restrict__ tih_b,
    const float* __restrict__ b_ih_f, const float* __restrict__ b_hh_f,
    const float* __restrict__ b_ih_b, const float* __restrict__ b_hh_b,
    const float* __restrict__ w_out,
    float* __restrict__ sc_f, float* __restrict__ sc_b)
{
    const int b = blockIdx.x, dir = blockIdx.y;
    const int len = lens[b];
    const int n = threadIdx.x;
    const float* Whh = dir ? thh_b : thh_f;
    const float* Wih = dir ? tih_b : tih_f;
    const float* bi = dir ? b_ih_b : b_ih_f;
    const float* bh = dir ? b_hh_b : b_hh_f;
    float* scout = dir ? sc_b : sc_f;

    __shared__ float x_s[256];
    __shared__ float h_s[256];
    __shared__ float g_s[1024];
    __shared__ float bias_s[1024];
    __shared__ float wout_s[20 * 257];
    __shared__ float part_s[20][8];

    bias_s[n] = bi[n] + bh[n];
    for (int e = n; e < 20 * 256; e += 1024)
        wout_s[(e >> 8) * 257 + (e & 255)] = w_out[(e >> 8) * 512 + dir * 256 + (e & 255)];
    if (n < 256) h_s[n] = 0.0f;
    float c = 0.0f;
    __syncthreads();

    const int sbase = b << 9;
    for (int t = 0; t < len; ++t) {
        if (n < 256) {
            int ti = dir ? (len - 1 - t) : t;
            int tok = sent[sbase + ti];
            x_s[n] = emb[(size_t)tok * NE + n];
        }
        __syncthreads();
        float acc = bias_s[n];
        const float* wi = Wih + n;
        const float* wh = Whh + n;
#pragma unroll 8
        for (int k = 0; k < 256; ++k) {
            acc = fmaf(wh[(size_t)(k << 10)], h_s[k], acc);
            acc = fmaf(wi[(size_t)(k << 10)], x_s[k], acc);
        }
        g_s[n] = acc;
        __syncthreads();
        if (n < 256) {
            float ig = g_s[n], fg = g_s[n + 256], gg = g_s[n + 512], og = g_s[n + 768];
            float cn = sigf_slow(fg) * c + sigf_slow(ig) * tanhf(gg);
            float hn = sigf_slow(og) * tanhf(cn);
            c = cn; h_s[n] = hn;
        }
        __syncthreads();
        if (n < 160) {
            const int tag = n >> 3, sl = n & 7;
            const float* wrow = wout_s + tag * 257;
            float s = 0.0f;
#pragma unroll 8
            for (int j = 0; j < 32; ++j) { int k = sl + (j << 3); s = fmaf(wrow[k], h_s[k], s); }
            part_s[tag][sl] = s;
        }
        __syncthreads();
        if (n < 20) {
            float s = part_s[n][0];
#pragma unroll
            for (int j = 1; j < 8; ++j) s += part_s[n][j];
            int tp = dir ? (len - 1 - t) : t;
            scout[(size_t)(sbase + tp) * 20 + n] = s;
        }
    }
}

__global__ __launch_bounds__(64) void k_viterbi_fb(
    const int* __restrict__ lens,
    const float* __restrict__ sc_f, const float* __restrict__ sc_b,
    const float* __restrict__ b_out, const float* __restrict__ trans,
    float* __restrict__ out)
{
    const int b = blockIdx.x;
    const int lane = threadIdx.x;
    const int len = lens[b];

    __shared__ float tr_s[20][21];
    __shared__ float fv_s[20];
    __shared__ float term_s[20];
    __shared__ float bo_s[20];
    __shared__ unsigned char bp_s[512][20];
    __shared__ unsigned char path_s[512];

    for (int e = lane; e < 400; e += 64) tr_s[e / 20][e % 20] = trans[e];
    if (lane < 20) { fv_s[lane] = (lane == TAG_START) ? 0.0f : NEGV; bo_s[lane] = b_out[lane]; }
    __syncthreads();

    const size_t sb = (size_t)(b << 9) * 20;
    for (int t = 0; t < len; ++t) {
        float m = 0.0f; int arg = 0;
        if (lane < 20) {
            m = fv_s[0] + tr_s[lane][0]; arg = 0;
#pragma unroll
            for (int k = 1; k < 20; ++k) {
                float v = fv_s[k] + tr_s[lane][k];
                if (v > m) { m = v; arg = k; }
            }
            m += sc_f[sb + t * 20 + lane] + sc_b[sb + t * 20 + lane] + bo_s[lane];
        }
        __syncthreads();
        if (lane < 20) { fv_s[lane] = m; bp_s[t][lane] = (unsigned char)arg; }
        __syncthreads();
    }
    if (lane < 20) term_s[lane] = fv_s[lane] + tr_s[TAG_STOP][lane];
    __syncthreads();
    if (lane == 0) {
        float m = term_s[0]; int arg = 0;
        for (int k = 1; k < 20; ++k) if (term_s[k] > m) { m = term_s[k]; arg = k; }
        out[b] = m;
        int cur = arg;
        path_s[len - 1] = (unsigned char)cur;
        for (int j = len - 1; j >= 1; --j) { cur = bp_s[j][cur]; path_s[j - 1] = (unsigned char)cur; }
    }
    __syncthreads();
    float* po = out + NB + ((size_t)b << 9);
    for (int p = lane; p < NL; p += 64) po[p] = (p < len) ? (float)path_s[p] : 0.0f;
}

// ===========================================================================
extern "C" void kernel_launch(void* const* d_in, const int* in_sizes, int n_in,
                              void* d_out, int out_size, void* d_ws, size_t ws_size,
                              hipStream_t stream)
{
    const int*   sent   = (const int*)d_in[0];
    const int*   lens   = (const int*)d_in[1];
    const float* emb    = (const float*)d_in[2];
    const float* w_ih_f = (const float*)d_in[3];
    const float* w_hh_f = (const float*)d_in[4];
    const float* b_ih_f = (const float*)d_in[5];
    const float* b_hh_f = (const float*)d_in[6];
    const float* w_ih_b = (const float*)d_in[7];
    const float* w_hh_b = (const float*)d_in[8];
    const float* b_ih_b = (const float*)d_in[9];
    const float* b_hh_b = (const float*)d_in[10];
    const float* w_out  = (const float*)d_in[11];
    const float* b_out  = (const float*)d_in[12];
    const float* trans  = (const float*)d_in[13];
    float* out = (float*)d_out;

    char* w = (char*)d_ws;
    // layout:
    //  whh16   @ 0        (1 MB)     wih16 @ 1048576 (1 MB)
    //  biasc   @ 2097152  (8 KB)     st_h  @ 2105344 (64 KB)
    //  st_c    @ 2170880  (128 KB)   hex   @ 2301952 (128 KB)
    //  flags   @ 2433024  (4 KB)     scores@ 2437120 (2.5 MB)
    //  hout    @ 5058560  (32 MB)    gin   @ 38612992 (CH*512 KB)
    const size_t base = 38612992;
    int CH = 0;
    const int chs[6] = {512, 256, 192, 128, 64, 32};
    for (int i = 0; i < 6; ++i)
        if (base + (size_t)chs[i] * 524288 <= ws_size) { CH = chs[i]; break; }

    if (CH) {
        ushortT* whh16 = (ushortT*)(w);
        ushortT* wih16 = (ushortT*)(w + 1048576);
        float*   biasc = (float*)(w + 2097152);
        ushortT* st_h  = (ushortT*)(w + 2105344);
        float*   st_c  = (float*)(w + 2170880);
        unsigned int* hexu = (unsigned int*)(w + 2301952);
        unsigned int* flags = (unsigned int*)(w + 2433024);
        float*   scores= (float*)(w + 2437120);
        ushortT* hout  = (ushortT*)(w + 5058560);
        float*   gin   = (float*)(w + base);

        hipMemsetAsync(flags, 0, 4096, stream);
        k_cvtw<<<dim3(1024, 4), 256, 0, stream>>>(w_hh_f, w_hh_b, w_ih_f, w_ih_b, whh16, wih16);
        k_bias<<<2, 1024, 0, stream>>>(b_ih_f, b_hh_f, b_ih_b, b_hh_b, biasc);

        for (int cs = 0; cs < NL; cs += CH) {
            k_gin_mfma<<<dim3(4, CH / 16, 4), 512, 0, stream>>>(
                sent, lens, emb, wih16, biasc, gin, cs, CH);
            k_rec_mfma<<<dim3(16), 512, 0, stream>>>(
                lens, whh16, gin, hout, st_h, st_c, hexu, flags, cs, CH);
        }
        k_scores_bf<<<dim3(16, 64), 256, 0, stream>>>(lens, hout, w_out, b_out, scores);
        k_viterbi_s<<<64, 64, 0, stream>>>(lens, scores, trans, out);
    } else {
        float* ws2   = (float*)d_ws;
        float* thh_f = ws2;
        float* thh_b = thh_f + 262144;
        float* tih_f = thh_b + 262144;
        float* tih_b = tih_f + 262144;
        float* sc_f  = tih_b + 262144;
        float* sc_b  = sc_f + (size_t)NB * NL * NT;

        k_transpose_fb<<<dim3(1024, 4), 256, 0, stream>>>(
            w_hh_f, w_hh_b, w_ih_f, w_ih_b, thh_f, thh_b, tih_f, tih_b);
        k_rec_fb<<<dim3(NB, 2), 1024, 0, stream>>>(
            sent, lens, emb, thh_f, thh_b, tih_f, tih_b,
            b_ih_f, b_hh_f, b_ih_b, b_hh_b, w_out, sc_f, sc_b);
        k_viterbi_fb<<<NB, 64, 0, stream>>>(lens, sc_f, sc_b, b_out, trans, out);
    }
}